// Round 9
// baseline (2986.264 us; speedup 1.0000x reference)
//
#include <hip/hip_runtime.h>
#include <hip/hip_bf16.h>

// Problem constants
#define B_   64
#define T_   512
#define I_   512
#define H_   512
#define G_   5
#define NROW 2560   // G*H gate rows per direction
#define KD   512    // K depth
#define NBLK_REC 128

typedef __attribute__((ext_vector_type(8))) __bf16 bf16x8;
typedef __attribute__((ext_vector_type(4))) float  f32x4;
typedef __attribute__((ext_vector_type(2))) unsigned long long u64x2;
typedef unsigned long long u64;

#define MFMA16(A, Bf, C) __builtin_amdgcn_mfma_f32_16x16x32_bf16(A, Bf, C, 0, 0, 0)

__device__ __forceinline__ unsigned short f2bf(float f) {
  unsigned u = __builtin_bit_cast(unsigned, f);
  u = (u + 0x7fffu + ((u >> 16) & 1u)) >> 16;   // RNE
  return (unsigned short)u;
}
__device__ __forceinline__ float bf2f(unsigned short s) {
  unsigned u = ((unsigned)s) << 16;
  return __builtin_bit_cast(float, u);
}
__device__ __forceinline__ float sigm(float x) { return 1.f / (1.f + __expf(-x)); }
__device__ __forceinline__ float tanh_fast(float x) {
  return 1.f - 2.f / (__expf(2.f * x) + 1.f);
}
__device__ __forceinline__ u64 al64(const u64* p) {
  return __hip_atomic_load(p, __ATOMIC_RELAXED, __HIP_MEMORY_SCOPE_AGENT);
}
__device__ __forceinline__ unsigned al32(const unsigned* p) {
  return __hip_atomic_load(p, __ATOMIC_RELAXED, __HIP_MEMORY_SCOPE_AGENT);
}
__device__ __forceinline__ void st32(unsigned* p, unsigned v) {
  __hip_atomic_store(p, v, __ATOMIC_RELAXED, __HIP_MEMORY_SCOPE_AGENT);
}

// ---------------- ws layout (bytes) ----------------
#define OFF_XP   ((size_t)0)
#define OFF_XB   ((size_t)335544320)
#define OFF_W2X  ((size_t)369098752)
#define OFF_W2H  ((size_t)374341632)
#define OFF_BIAS ((size_t)379584512)
#define OFF_HB   ((size_t)379604992)
#define OFF_BAR  ((size_t)379867136)
#define WS_NEED  ((size_t)379871232)

// ---------------- sentinel (ws too small) ----------------
__global__ void k_sentinel(float* out, int n) {
  int i = blockIdx.x * 256 + threadIdx.x;
  if (i < n) out[i] = 10000.0f;
}

// ---------------- converts ----------------
__global__ void k_cvt_weights(const float* __restrict__ Wx_f, const float* __restrict__ Wh_f,
                              const float* __restrict__ Wx_b, const float* __restrict__ Wh_b,
                              const float* __restrict__ bx_f, const float* __restrict__ bh_f,
                              const float* __restrict__ bx_b, const float* __restrict__ bh_b,
                              unsigned short* __restrict__ W2x, unsigned short* __restrict__ W2h,
                              float* __restrict__ bias2) {
  int idx = blockIdx.x * 256 + threadIdx.x;       // exactly 2*NROW*KD threads
  int dir = idx / (NROW * KD);
  int r   = idx % (NROW * KD);
  W2x[idx] = f2bf(dir ? Wx_b[r] : Wx_f[r]);
  W2h[idx] = f2bf(dir ? Wh_b[r] : Wh_f[r]);
  if (idx < 2 * NROW) {
    int d2 = idx / NROW, n = idx % NROW;
    bias2[idx] = d2 ? (bx_b[n] + bh_b[n]) : (bx_f[n] + bh_f[n]);
  }
}

__global__ void k_cvt_x(const float* __restrict__ x, unsigned short* __restrict__ xb) {
  int idx = blockIdx.x * 256 + threadIdx.x;       // exactly B*T*I threads
  xb[idx] = f2bf(x[idx]);
}

__global__ void k_zero_h(unsigned short* __restrict__ hb, unsigned* __restrict__ bar) {
  int idx = blockIdx.x * 256 + threadIdx.x;       // exactly 2*2*B*H threads
  hb[idx] = 0;
  if (idx < 1024) bar[idx] = 0;
}

// ---------------- phase 1: xp = Wx · x^T (+bias), both dirs ----------------
__global__ __launch_bounds__(256) void k_gemm_xp(
    const unsigned short* __restrict__ W2x,   // [2][NROW][KD]
    const unsigned short* __restrict__ xb,    // [B][T][I]
    const float* __restrict__ bias2,          // [2][NROW]
    unsigned short* __restrict__ xp)          // [2][T][NROW][B]
{
  const int tid = threadIdx.x;
  const int lane = tid & 63, wv = tid >> 6;
  int bz = blockIdx.x;
  const int dir = bz / (20 * 256); bz %= (20 * 256);
  const int nblk = bz / 256, mblk = bz % 256;
  const int n0 = nblk * 128, m0 = mblk * 128;
  const int l15 = lane & 15, l4 = lane >> 4;
  const int nh = wv >> 1, mh = wv & 1;

  __shared__ unsigned short Al[128 * 72];
  __shared__ unsigned short Bl[128 * 72];

  const unsigned short* Wd = W2x + (size_t)dir * NROW * KD;

  f32x4 acc[4][4];
  f32x4 zz = {0.f, 0.f, 0.f, 0.f};
#pragma unroll
  for (int i = 0; i < 4; ++i)
#pragma unroll
    for (int j = 0; j < 4; ++j) acc[i][j] = zz;

  for (int k0 = 0; k0 < KD; k0 += 64) {
#pragma unroll
    for (int j = 0; j < 4; ++j) {
      int sg = j * 256 + tid;
      int row = sg >> 3, ko = (sg & 7) * 8;
      bf16x8 va = *(const bf16x8*)(Wd + (size_t)(n0 + row) * KD + k0 + ko);
      *(bf16x8*)(Al + row * 72 + ko) = va;
      int m = m0 + row;
      int ss = m >> 6, b = m & 63;
      int trow = dir ? (T_ - 1 - ss) : ss;
      bf16x8 vb = *(const bf16x8*)(xb + ((size_t)b * T_ + trow) * I_ + k0 + ko);
      *(bf16x8*)(Bl + row * 72 + ko) = vb;
    }
    __syncthreads();
#pragma unroll
    for (int kk = 0; kk < 2; ++kk) {
      bf16x8 af[4], bfr[4];
#pragma unroll
      for (int f = 0; f < 4; ++f) {
        af[f]  = *(const bf16x8*)(Al + (nh * 64 + f * 16 + l15) * 72 + kk * 32 + l4 * 8);
        bfr[f] = *(const bf16x8*)(Bl + (mh * 64 + f * 16 + l15) * 72 + kk * 32 + l4 * 8);
      }
#pragma unroll
      for (int fi = 0; fi < 4; ++fi)
#pragma unroll
        for (int fj = 0; fj < 4; ++fj)
          acc[fi][fj] = MFMA16(af[fi], bfr[fj], acc[fi][fj]);
    }
    __syncthreads();
  }

#pragma unroll
  for (int fi = 0; fi < 4; ++fi) {
#pragma unroll
    for (int fj = 0; fj < 4; ++fj) {
#pragma unroll
      for (int r = 0; r < 4; ++r) {
        int n = n0 + nh * 64 + fi * 16 + l4 * 4 + r;
        int m = m0 + mh * 64 + fj * 16 + l15;
        int ss = m >> 6, b = m & 63;
        float v = acc[fi][fj][r] + bias2[dir * NROW + n];
        xp[(((size_t)dir * T_ + ss) * NROW + n) * 64 + b] = f2bf(v);
      }
    }
  }
}

// ---------------- phase 2 helpers ----------------
// xp stream index math: 640 u32 per (dir, step, block): g = ji>>7, ul, bpair
__device__ __forceinline__ unsigned xp_ld(const unsigned* base, int c, int ji) {
  int g = ji >> 7, r = ji & 127, ul = r >> 5, bp = r & 31;
  return base[(g * H_ + c * 4 + ul) * 32 + bp];
}
__device__ __forceinline__ void xp_st(unsigned short* xl, int ji, unsigned v) {
  int g = ji >> 7, r = ji & 127, ul = r >> 5, bp = r & 31;
  *(unsigned*)&xl[(g * 4 + ul) * 72 + bp * 2] = v;
}

__device__ __forceinline__ void poll_flags(const unsigned* fl, unsigned tgt, int lane) {
  __builtin_amdgcn_sched_barrier(0);
  for (;;) {
    unsigned a = al32(fl + lane);
    unsigned b = al32(fl + 64 + lane);
    unsigned v = a < b ? a : b;
    if (!__any(v < tgt)) break;
    __builtin_amdgcn_s_sleep(1);
  }
  __builtin_amdgcn_sched_barrier(0);
}

// GEMM part of one dir-phase: h loads + MFMA + xp commit + gate dump
__device__ __forceinline__ void gemm_part(
    int tid, int wv, int l15, int l4,
    const unsigned short* __restrict__ wl,   // [20][520] this dir
    float* __restrict__ gl,                  // [64][36]
    unsigned short* __restrict__ xl,         // [5][4][72]
    const unsigned short* hc,                // dir-buf (current)
    unsigned x0, unsigned x1, unsigned x2)
{
  const u64* hq = (const u64*)hc;
  int batch = wv * 16 + l15;
  u64 lo[16], hi[16];
#pragma unroll
  for (int t = 0; t < 16; ++t) {
    int c = t * 8 + l4 * 2;
    lo[t] = al64(hq + c * 64 + batch);
    hi[t] = al64(hq + (c + 1) * 64 + batch);
  }
  const unsigned short* wb0 = wl + l15 * 520 + l4 * 8;
  const unsigned short* wb1 = wl + ((l15 < 4) ? (16 + l15) : 0) * 520 + l4 * 8;

  f32x4 zz = {0.f, 0.f, 0.f, 0.f};
  f32x4 a0 = zz, b0 = zz, a1 = zz, b1 = zz;
#pragma unroll
  for (int ks = 0; ks < 8; ++ks) {
    u64x2 t2 = {lo[ks], hi[ks]};
    bf16x8 a = __builtin_bit_cast(bf16x8, t2);
    a0 = MFMA16(a, *(const bf16x8*)(wb0 + ks * 32), a0);
    a1 = MFMA16(a, *(const bf16x8*)(wb1 + ks * 32), a1);
  }
#pragma unroll
  for (int ks = 8; ks < 16; ++ks) {
    u64x2 t2 = {lo[ks], hi[ks]};
    bf16x8 a = __builtin_bit_cast(bf16x8, t2);
    b0 = MFMA16(a, *(const bf16x8*)(wb0 + ks * 32), b0);
    b1 = MFMA16(a, *(const bf16x8*)(wb1 + ks * 32), b1);
  }
  f32x4 acc0 = a0 + b0, acc1 = a1 + b1;

  // commit this step's xp to LDS (loads are oldest vmem -> already retired)
  xp_st(xl, tid, x0);
  xp_st(xl, tid + 256, x1);
  if (tid < 128) xp_st(xl, tid + 512, x2);

  // dump gates: row(M)=batch=(l4*4+rr), col(N)=gate row
#pragma unroll
  for (int rr = 0; rr < 4; ++rr) {
    int b = wv * 16 + l4 * 4 + rr;
    gl[b * 36 + l15]      = acc0[rr];
    gl[b * 36 + 16 + l15] = acc1[rr];
  }
}

// pointwise update for this thread's single cell (bb = tid>>2, up = tid&3)
__device__ __forceinline__ float cell_update(
    int tid, const float* __restrict__ gl, const unsigned short* __restrict__ xl,
    float& kst, float& kpst)
{
  int bb = tid >> 2, up = tid & 3;
  float g0 = gl[bb * 36 + 0  + up] + bf2f(xl[(0  + up) * 72 + bb]);
  float g1 = gl[bb * 36 + 4  + up] + bf2f(xl[(4  + up) * 72 + bb]);
  float g2 = gl[bb * 36 + 8  + up] + bf2f(xl[(8  + up) * 72 + bb]);
  float g3 = gl[bb * 36 + 12 + up] + bf2f(xl[(12 + up) * 72 + bb]);
  float g4 = gl[bb * 36 + 16 + up] + bf2f(xl[(16 + up) * 72 + bb]);
  float f0 = sigm(g0), i0 = sigm(g1), o0 = sigm(g2), uu = sigm(g3), tk = tanh_fast(g4);
  kpst = uu * tk + (1.f - uu) * kpst;
  kst  = f0 * kst + i0 * kpst;
  return o0 * tanh_fast(kst);
}

// ---------------- phase 2: interleaved f/b persistent kernel ----------------
// 128 blocks x 256 threads. Block bid owns units bid*4..bid*4+3 of BOTH dirs.
// Per superstep each wave advances dir-f AND dir-b one step; each dir's sync
// (store-ack, flag hop, poll detect) hides under the other dir's compute.
// Flag publishes ride existing __syncthreads (vmcnt(0) drains = store acked).
__global__ __launch_bounds__(256, 1) void k_recurrent(
    const unsigned short* __restrict__ W2h,  // [2][NROW][KD]
    const unsigned short* __restrict__ xp,   // [2][T][NROW][B]
    unsigned short* __restrict__ hbuf,       // [buf][dir][128 chunks][64 b][4 u]
    float* __restrict__ out,                 // [B][T][2H]
    unsigned* __restrict__ bar)              // f flags [0..127], b flags [128..255]
{
  const int tid = threadIdx.x;
  const int lane = tid & 63, wv = tid >> 6;
  const int bid = blockIdx.x;                // chunk id, 0..127
  const int l15 = lane & 15, l4 = lane >> 4;

  __shared__ unsigned short w_sh[2][20 * 520];     // 41.6 KB
  __shared__ float          g_sh[2][64 * 36];      // 18.4 KB
  __shared__ unsigned short x_sh[2][5 * 4 * 72];   //  5.8 KB

  // ---- stage Wh rows for this block's 4 units, both dirs ----
  // 2 dirs x 20 rows x 64 segs(16B) = 2560 segs  (round-8 bug: had 1280)
#pragma unroll
  for (int it = 0; it < 10; ++it) {
    int seg = it * 256 + tid;
    int d = seg / 1280, rs = seg % 1280;
    int r = rs >> 6, c8 = rs & 63;       // r = g*4+ul in [0,20), c8 = 16B col
    int g = r >> 2, ul = r & 3;
    const unsigned short* src =
        W2h + ((size_t)d * NROW + g * H_ + bid * 4 + ul) * KD + c8 * 8;
    *(bf16x8*)(&w_sh[d][r * 520 + c8 * 8]) = *(const bf16x8*)src;
  }
  __syncthreads();

  // h buffers: [buf][dir]
  const unsigned short* hcF = hbuf;                          // buf0 dir f
  unsigned short*       hnF = hbuf + (size_t)2 * B_ * H_;    // buf1 dir f
  const unsigned short* hcB = hbuf + (size_t)1 * B_ * H_;    // buf0 dir b
  unsigned short*       hnB = hbuf + (size_t)3 * B_ * H_;    // buf1 dir b
  unsigned* flagsF = bar;
  unsigned* flagsB = bar + 128;

  const unsigned short* xpdF = xp;
  const unsigned short* xpdB = xp + (size_t)T_ * NROW * 64;

  float kstF = 0.f, kpstF = 0.f, kstB = 0.f, kpstB = 0.f;
  const int bb = tid >> 2, up = tid & 3;

  // prefetch xp step 0, both dirs
  unsigned fx0, fx1, fx2, bx0, bx1, bx2;
  {
    const unsigned* nf = (const unsigned*)xpdF;
    const unsigned* nb = (const unsigned*)xpdB;
    fx0 = xp_ld(nf, bid, tid); fx1 = xp_ld(nf, bid, tid + 256);
    fx2 = (tid < 128) ? xp_ld(nf, bid, tid + 512) : 0;
    bx0 = xp_ld(nb, bid, tid); bx1 = xp_ld(nb, bid, tid + 256);
    bx2 = (tid < 128) ? xp_ld(nb, bid, tid + 512) : 0;
  }

  for (int s = 0; s < T_; ++s) {
    // ---------- dir f ----------
    if (s) poll_flags(flagsF, (unsigned)s, lane);
    gemm_part(tid, wv, l15, l4, w_sh[0], g_sh[0], x_sh[0], hcF, fx0, fx1, fx2);
    __syncthreads();                               // f gates ready
    float hvF = cell_update(tid, g_sh[0], x_sh[0], kstF, kpstF);
    {
      unsigned hw = f2bf(hvF);
      unsigned pn = (unsigned)__shfl_xor((int)hw, 1);
      if (!(tid & 1))
        st32((unsigned*)(hnF + bid * 256 + bb * 4 + up), hw | (pn << 16));
      out[((size_t)bb * T_ + s) * (2 * H_) + bid * 4 + up] = hvF;
    }

    // ---------- dir b ----------
    if (s) poll_flags(flagsB, (unsigned)s, lane);
    gemm_part(tid, wv, l15, l4, w_sh[1], g_sh[1], x_sh[1], hcB, bx0, bx1, bx2);
    __syncthreads();                               // b gates ready; also drains
                                                   // f h-store (in-order vmcnt)
    if (tid == 0 && s + 1 < T_)
      st32(&flagsF[bid], (unsigned)(s + 1));       // publish f (ack guaranteed)
    float hvB = cell_update(tid, g_sh[1], x_sh[1], kstB, kpstB);
    {
      unsigned hw = f2bf(hvB);
      unsigned pn = (unsigned)__shfl_xor((int)hw, 1);
      if (!(tid & 1))
        st32((unsigned*)(hnB + bid * 256 + bb * 4 + up), hw | (pn << 16));
      out[((size_t)bb * T_ + (T_ - 1 - s)) * (2 * H_) + H_ + bid * 4 + up] = hvB;
    }
    __syncthreads();                               // drains b h-store
    if (tid == 0 && s + 1 < T_)
      st32(&flagsB[bid], (unsigned)(s + 1));       // publish b

    // prefetch xp for s+1 (clamped) — consumed after next poll+MFMA
    int sp = (s + 1 < T_) ? s + 1 : s;
    const unsigned* nf = (const unsigned*)(xpdF + (size_t)sp * NROW * 64);
    const unsigned* nb = (const unsigned*)(xpdB + (size_t)sp * NROW * 64);
    fx0 = xp_ld(nf, bid, tid); fx1 = xp_ld(nf, bid, tid + 256);
    fx2 = (tid < 128) ? xp_ld(nf, bid, tid + 512) : 0;
    bx0 = xp_ld(nb, bid, tid); bx1 = xp_ld(nb, bid, tid + 256);
    bx2 = (tid < 128) ? xp_ld(nb, bid, tid + 512) : 0;

    // rotate h buffers
    const unsigned short* t1 = hcF; hcF = hnF; hnF = (unsigned short*)t1;
    const unsigned short* t2 = hcB; hcB = hnB; hnB = (unsigned short*)t2;
  }
}

// ---------------- launch ----------------
extern "C" void kernel_launch(void* const* d_in, const int* in_sizes, int n_in,
                              void* d_out, int out_size, void* d_ws, size_t ws_size,
                              hipStream_t stream) {
  const float* x    = (const float*)d_in[0];
  const float* Wx_f = (const float*)d_in[1];
  const float* bx_f = (const float*)d_in[2];
  const float* Wh_f = (const float*)d_in[3];
  const float* bh_f = (const float*)d_in[4];
  const float* Wx_b = (const float*)d_in[5];
  const float* bx_b = (const float*)d_in[6];
  const float* Wh_b = (const float*)d_in[7];
  const float* bh_b = (const float*)d_in[8];
  float* out = (float*)d_out;

  if (ws_size < WS_NEED) {
    k_sentinel<<<(out_size + 255) / 256, 256, 0, stream>>>(out, out_size);
    return;
  }

  char* ws = (char*)d_ws;
  unsigned short* xp    = (unsigned short*)(ws + OFF_XP);
  unsigned short* xb    = (unsigned short*)(ws + OFF_XB);
  unsigned short* W2x   = (unsigned short*)(ws + OFF_W2X);
  unsigned short* W2h   = (unsigned short*)(ws + OFF_W2H);
  float*          bias2 = (float*)(ws + OFF_BIAS);
  unsigned short* hbuf  = (unsigned short*)(ws + OFF_HB);
  unsigned*       bar   = (unsigned*)(ws + OFF_BAR);

  k_cvt_weights<<<(2 * NROW * KD) / 256, 256, 0, stream>>>(
      Wx_f, Wh_f, Wx_b, Wh_b, bx_f, bh_f, bx_b, bh_b, W2x, W2h, bias2);
  k_cvt_x<<<(B_ * T_ * I_) / 256, 256, 0, stream>>>(x, xb);
  k_zero_h<<<(2 * 2 * B_ * H_) / 256, 256, 0, stream>>>(hbuf, bar);
  k_gemm_xp<<<2 * 20 * 256, 256, 0, stream>>>(W2x, xb, bias2, xp);
  k_recurrent<<<NBLK_REC, 256, 0, stream>>>(W2h, xp, hbuf, out, bar);
}